// Round 2
// baseline (7072.951 us; speedup 1.0000x reference)
//
#include <hip/hip_runtime.h>
#include <stdint.h>

// GRU: T=2048, B=128, I=256, H=256.
// Phase 1 (per chunk): gi = x @ w_ih^T + b_ih  -> bf16 in d_ws  (MFMA GEMM)
// Phase 2 (per chunk): serial scan, 128 WGs (one per batch row).
//   Thread layout: j = tid>>1 (hidden unit), q = tid&1 (k-half of 128).
//   w_hh bf16-packed in 192 regs/thread; gh via v_dot2_f32_bf16.
//   h broadcast via double-buffered 512B LDS buffer; ONE barrier per step.
//   k-half reduce via __shfl_xor(1) (adjacent lanes), no LDS round trip.

#define T_SEQ 2048
#define BATCH 128
#define IDIM  256
#define HDIM  256
#define G3    768   // 3*H

typedef float f32x4 __attribute__((ext_vector_type(4)));
typedef short bf16x8 __attribute__((ext_vector_type(8)));

__device__ __forceinline__ uint16_t f2bf(float f) {
  union { float f; uint32_t u; } v; v.f = f;
  uint32_t u = v.u;
  return (uint16_t)((u + 0x7fffu + ((u >> 16) & 1u)) >> 16);  // RNE
}
__device__ __forceinline__ uint32_t pack2(float a, float b) {
  return (uint32_t)f2bf(a) | ((uint32_t)f2bf(b) << 16);
}
__device__ __forceinline__ float bf2f(uint16_t h) {
  union { uint32_t u; float f; } v; v.u = ((uint32_t)h) << 16;
  return v.f;
}
__device__ __forceinline__ float dot2bf(uint32_t w, uint32_t h, float acc) {
#if defined(__has_builtin)
#if __has_builtin(__builtin_amdgcn_fdot2_f32_bf16)
  typedef __bf16 v2bf __attribute__((ext_vector_type(2)));
  union U { uint32_t u; v2bf v; };
  U a, b; a.u = w; b.u = h;
  return __builtin_amdgcn_fdot2_f32_bf16(a.v, b.v, acc, false);
#else
  asm("v_dot2_f32_bf16 %0, %1, %2, %0" : "+v"(acc) : "v"(w), "v"(h));
  return acc;
#endif
#else
  asm("v_dot2_f32_bf16 %0, %1, %2, %0" : "+v"(acc) : "v"(w), "v"(h));
  return acc;
#endif
}

// ---------------------------------------------------------------------------
// Phase 1: gi GEMM.  256 WGs x 512 thr (8 waves). Wave w owns N-slice
// [w*96, w*96+96) with w_ih frags persistent in VGPRs (192 dwords/thread).
// ---------------------------------------------------------------------------
#define GEMM_NT 6
#define GEMM_KS 8
#define LDSROW  1552  // padded row stride (bytes)

__global__ __launch_bounds__(512, 2)
void gi_gemm(const float* __restrict__ x, const float* __restrict__ w_ih,
             const float* __restrict__ b_ih, uint16_t* __restrict__ gi,
             int tiles) {
  __shared__ __align__(16) uint8_t lds_raw[16 * LDSROW];
  const int tid  = threadIdx.x;
  const int lane = tid & 63;
  const int wv   = tid >> 6;       // wave 0..7
  const int l15  = lane & 15;
  const int lk   = lane >> 4;      // 0..3

  bf16x8 bfrag[GEMM_NT][GEMM_KS];
  float  bias[GEMM_NT];
#pragma unroll
  for (int nt = 0; nt < GEMM_NT; ++nt) {
    const int col = wv * 96 + nt * 16 + l15;
    bias[nt] = b_ih[col];
#pragma unroll
    for (int ks = 0; ks < GEMM_KS; ++ks) {
      const int kb = ks * 32 + lk * 8;
      const float4* p = (const float4*)(w_ih + (size_t)col * IDIM + kb);
      float4 w0 = p[0], w1 = p[1];
      union { uint32_t u[4]; bf16x8 v; } pk;
      pk.u[0] = pack2(w0.x, w0.y); pk.u[1] = pack2(w0.z, w0.w);
      pk.u[2] = pack2(w1.x, w1.y); pk.u[3] = pack2(w1.z, w1.w);
      bfrag[nt][ks] = pk.v;
    }
  }

  for (int tile = blockIdx.x; tile < tiles; tile += gridDim.x) {
    const int m0 = tile * 16;
    f32x4 acc[GEMM_NT];
#pragma unroll
    for (int nt = 0; nt < GEMM_NT; ++nt) {
      f32x4 z = {0.f, 0.f, 0.f, 0.f};
      acc[nt] = z;
    }
#pragma unroll
    for (int ks = 0; ks < GEMM_KS; ++ks) {
      const float4* p = (const float4*)(x + (size_t)(m0 + l15) * IDIM + ks * 32 + lk * 8);
      float4 a0 = p[0], a1 = p[1];
      union { uint32_t u[4]; bf16x8 v; } pk;
      pk.u[0] = pack2(a0.x, a0.y); pk.u[1] = pack2(a0.z, a0.w);
      pk.u[2] = pack2(a1.x, a1.y); pk.u[3] = pack2(a1.z, a1.w);
#pragma unroll
      for (int nt = 0; nt < GEMM_NT; ++nt)
        acc[nt] = __builtin_amdgcn_mfma_f32_16x16x32_bf16(pk.v, bfrag[nt][ks], acc[nt], 0, 0, 0);
    }
#pragma unroll
    for (int nt = 0; nt < GEMM_NT; ++nt) {
      const int col = wv * 96 + nt * 16 + l15;
#pragma unroll
      for (int i = 0; i < 4; ++i) {
        const int row = lk * 4 + i;
        *(uint16_t*)(lds_raw + row * LDSROW + col * 2) = f2bf(acc[nt][i] + bias[nt]);
      }
    }
    __syncthreads();
    {
      const int row = tid >> 5, c = tid & 31;
      const uint4* src = (const uint4*)(lds_raw + row * LDSROW + c * 48);
      uint4* dst = (uint4*)((uint8_t*)gi + (size_t)(m0 + row) * G3 * 2 + c * 48);
      dst[0] = src[0]; dst[1] = src[1]; dst[2] = src[2];
    }
    __syncthreads();
  }
}

// ---------------------------------------------------------------------------
// Phase 2: serial scan. 128 WGs x 512 thr. j = tid>>1, q = tid&1.
// ---------------------------------------------------------------------------
__global__ __launch_bounds__(512, 2)
void gru_scan(const uint16_t* __restrict__ gi, const float* __restrict__ w_hh,
              const float* __restrict__ b_hh, const float* __restrict__ h0,
              float* __restrict__ hstate, float* __restrict__ out,
              int t0, int cT) {
  __shared__ __align__(16) uint4 hbuf[2][32];   // double-buffered 256 bf16 h
  const int b   = blockIdx.x;
  const int tid = threadIdx.x;
  const int j   = tid >> 1;   // hidden unit 0..255
  const int q   = tid & 1;    // k-half 0..1

  // First-step gi loads (issued early, covered by weight preload)
  const uint16_t* gib = gi + (size_t)b * G3 + j;
  float gr = bf2f(gib[0]), gz = bf2f(gib[256]), gn = bf2f(gib[512]);

  // Weight preload: 3 gates x 64 packed bf16 pairs (k-half q)
  uint32_t wr[64], wz[64], wn[64];
#pragma unroll
  for (int p = 0; p < 64; ++p) {
    float2 a = ((const float2*)(w_hh + (size_t)(0 * 256 + j) * HDIM + q * 128))[p];
    float2 c = ((const float2*)(w_hh + (size_t)(1 * 256 + j) * HDIM + q * 128))[p];
    float2 d = ((const float2*)(w_hh + (size_t)(2 * 256 + j) * HDIM + q * 128))[p];
    wr[p] = pack2(a.x, a.y);
    wz[p] = pack2(c.x, c.y);
    wn[p] = pack2(d.x, d.y);
  }
  const float bhr = b_hh[j], bhz = b_hh[256 + j], bhn = b_hh[512 + j];

  float h = (t0 == 0) ? h0[b * HDIM + j] : hstate[b * HDIM + j];
  if (q == 0) ((uint16_t*)&hbuf[0][0])[j] = f2bf(h);
  __syncthreads();

  float* outp = out + (size_t)t0 * BATCH * HDIM + (size_t)b * HDIM + j;

  for (int tt = 0; tt < cT; ++tt) {
    const int cur = tt & 1;
    // Hoisted h reads: 16 x ds_read_b128, one lgkm drain for the step
    uint4 hv[16];
#pragma unroll
    for (int p = 0; p < 16; ++p) hv[p] = hbuf[cur][(q << 4) + p];
    // Prefetch next step's gi (covered by the dot chain below)
    float grn = 0.f, gzn = 0.f, gnn = 0.f;
    if (tt + 1 < cT) {
      const uint16_t* p2 = gib + (size_t)(tt + 1) * BATCH * G3;
      grn = bf2f(p2[0]); gzn = bf2f(p2[256]); gnn = bf2f(p2[512]);
    }

    float ar = 0.f, az = 0.f, an = 0.f;
#pragma unroll
    for (int p = 0; p < 16; ++p) {
      ar = dot2bf(wr[p * 4 + 0], hv[p].x, ar);
      az = dot2bf(wz[p * 4 + 0], hv[p].x, az);
      an = dot2bf(wn[p * 4 + 0], hv[p].x, an);
      ar = dot2bf(wr[p * 4 + 1], hv[p].y, ar);
      az = dot2bf(wz[p * 4 + 1], hv[p].y, az);
      an = dot2bf(wn[p * 4 + 1], hv[p].y, an);
      ar = dot2bf(wr[p * 4 + 2], hv[p].z, ar);
      az = dot2bf(wz[p * 4 + 2], hv[p].z, az);
      an = dot2bf(wn[p * 4 + 2], hv[p].z, an);
      ar = dot2bf(wr[p * 4 + 3], hv[p].w, ar);
      az = dot2bf(wz[p * 4 + 3], hv[p].w, az);
      an = dot2bf(wn[p * 4 + 3], hv[p].w, an);
    }
    // k-half reduce: adjacent lanes (same j, q=0/1)
    ar += __shfl_xor(ar, 1);
    az += __shfl_xor(az, 1);
    an += __shfl_xor(an, 1);

    // Gates (computed redundantly by both q-lanes; no divergence)
    float sr = gr + ar + bhr;
    float sz = gz + az + bhz;
    float hn = an + bhn;
    float r = 1.f / (1.f + __expf(-sr));
    float z = 1.f / (1.f + __expf(-sz));
    float xn = gn + r * hn;
    float e = __expf(-2.f * xn);
    float n = 1.f - 2.f * e / (1.f + e);    // tanh(xn)
    h = (1.f - z) * n + z * h;

    if (q == 0) {
      outp[(size_t)tt * BATCH * HDIM] = h;
      ((uint16_t*)&hbuf[cur ^ 1][0])[j] = f2bf(h);
    }
    gr = grn; gz = gzn; gn = gnn;
    __syncthreads();
  }

  if (q == 0) {
    hstate[b * HDIM + j] = h;
    if (t0 + cT == T_SEQ)
      out[(size_t)T_SEQ * BATCH * HDIM + (size_t)b * HDIM + j] = h;
  }
}

// ---------------------------------------------------------------------------
extern "C" void kernel_launch(void* const* d_in, const int* in_sizes, int n_in,
                              void* d_out, int out_size, void* d_ws, size_t ws_size,
                              hipStream_t stream) {
  const float* x    = (const float*)d_in[0];
  const float* h0   = (const float*)d_in[1];
  const float* w_ih = (const float*)d_in[2];
  const float* w_hh = (const float*)d_in[3];
  const float* b_ih = (const float*)d_in[4];
  const float* b_hh = (const float*)d_in[5];
  float* out = (float*)d_out;

  const size_t HST = 1 << 17;  // 128 KB reserved for fp32 h carry state
  float* hstate = (float*)d_ws;
  uint16_t* gi = (uint16_t*)((char*)d_ws + HST);

  const size_t per_t = (size_t)BATCH * G3 * 2;  // bytes of gi per timestep
  size_t cap = (ws_size > HST) ? (ws_size - HST) / per_t : 0;
  int chunk = (int)((cap < (size_t)T_SEQ) ? cap : (size_t)T_SEQ);
  if (chunk < 1) chunk = 1;

  for (int t0 = 0; t0 < T_SEQ; t0 += chunk) {
    const int cT = (T_SEQ - t0 < chunk) ? (T_SEQ - t0) : chunk;
    const int tiles = cT * BATCH / 16;
    gi_gemm<<<256, 512, 0, stream>>>(x + (size_t)t0 * BATCH * IDIM, w_ih, b_ih, gi, tiles);
    gru_scan<<<128, 512, 0, stream>>>(gi, w_hh, b_hh, h0, hstate, out, t0, cT);
  }
}

// Round 3
// 3752.981 us; speedup vs baseline: 1.8846x; 1.8846x over previous
//
#include <hip/hip_runtime.h>
#include <stdint.h>

// GRU: T=2048, B=128, I=256, H=256.
// Phase 1: gi = x @ w_ih^T + b_ih  -> bf16 in d_ws  (MFMA GEMM)
// Phase 2: serial scan, 128 WGs (one per batch row), 512 thr.
//   j = tid>>1 (hidden unit), q = tid&1 (k-half). w_hh bf16-packed in 192
//   VGPRs/thread (REQUIRES the 256-VGPR cap from __launch_bounds__(512,1) —
//   at 128 VGPRs this design scratch-spills and runs 4x slower).
//   h broadcast via double-buffered, SKEWED LDS buffer (q=1 half at uint4
//   idx 17 so the wave's two b128 addresses hit disjoint bank groups).
//   One __syncthreads per step; k-half reduce via __shfl_xor(1).

#define T_SEQ 2048
#define BATCH 128
#define IDIM  256
#define HDIM  256
#define G3    768   // 3*H

typedef float f32x4 __attribute__((ext_vector_type(4)));
typedef short bf16x8 __attribute__((ext_vector_type(8)));

__device__ __forceinline__ uint16_t f2bf(float f) {
  union { float f; uint32_t u; } v; v.f = f;
  uint32_t u = v.u;
  return (uint16_t)((u + 0x7fffu + ((u >> 16) & 1u)) >> 16);  // RNE
}
__device__ __forceinline__ uint32_t pack2(float a, float b) {
  return (uint32_t)f2bf(a) | ((uint32_t)f2bf(b) << 16);
}
__device__ __forceinline__ float bf2f(uint16_t h) {
  union { uint32_t u; float f; } v; v.u = ((uint32_t)h) << 16;
  return v.f;
}
__device__ __forceinline__ float dot2bf(uint32_t w, uint32_t h, float acc) {
#if defined(__has_builtin)
#if __has_builtin(__builtin_amdgcn_fdot2_f32_bf16)
  typedef __bf16 v2bf __attribute__((ext_vector_type(2)));
  union U { uint32_t u; v2bf v; };
  U a, b; a.u = w; b.u = h;
  return __builtin_amdgcn_fdot2_f32_bf16(a.v, b.v, acc, false);
#else
  asm("v_dot2_f32_bf16 %0, %1, %2, %0" : "+v"(acc) : "v"(w), "v"(h));
  return acc;
#endif
#else
  asm("v_dot2_f32_bf16 %0, %1, %2, %0" : "+v"(acc) : "v"(w), "v"(h));
  return acc;
#endif
}

// ---------------------------------------------------------------------------
// Phase 1: gi GEMM.  256 WGs x 512 thr (8 waves). Wave w owns N-slice
// [w*96, w*96+96) with w_ih frags persistent in VGPRs (192 dwords/thread).
// ---------------------------------------------------------------------------
#define GEMM_NT 6
#define GEMM_KS 8
#define LDSROW  1552  // padded row stride (bytes)

__global__ __launch_bounds__(512, 1)
void gi_gemm(const float* __restrict__ x, const float* __restrict__ w_ih,
             const float* __restrict__ b_ih, uint16_t* __restrict__ gi,
             int tiles) {
  __shared__ __align__(16) uint8_t lds_raw[16 * LDSROW];
  const int tid  = threadIdx.x;
  const int lane = tid & 63;
  const int wv   = tid >> 6;       // wave 0..7
  const int l15  = lane & 15;
  const int lk   = lane >> 4;      // 0..3

  bf16x8 bfrag[GEMM_NT][GEMM_KS];
  float  bias[GEMM_NT];
#pragma unroll
  for (int nt = 0; nt < GEMM_NT; ++nt) {
    const int col = wv * 96 + nt * 16 + l15;
    bias[nt] = b_ih[col];
#pragma unroll
    for (int ks = 0; ks < GEMM_KS; ++ks) {
      const int kb = ks * 32 + lk * 8;
      const float4* p = (const float4*)(w_ih + (size_t)col * IDIM + kb);
      float4 w0 = p[0], w1 = p[1];
      union { uint32_t u[4]; bf16x8 v; } pk;
      pk.u[0] = pack2(w0.x, w0.y); pk.u[1] = pack2(w0.z, w0.w);
      pk.u[2] = pack2(w1.x, w1.y); pk.u[3] = pack2(w1.z, w1.w);
      bfrag[nt][ks] = pk.v;
    }
  }

  for (int tile = blockIdx.x; tile < tiles; tile += gridDim.x) {
    const int m0 = tile * 16;
    f32x4 acc[GEMM_NT];
#pragma unroll
    for (int nt = 0; nt < GEMM_NT; ++nt) {
      f32x4 z = {0.f, 0.f, 0.f, 0.f};
      acc[nt] = z;
    }
#pragma unroll
    for (int ks = 0; ks < GEMM_KS; ++ks) {
      const float4* p = (const float4*)(x + (size_t)(m0 + l15) * IDIM + ks * 32 + lk * 8);
      float4 a0 = p[0], a1 = p[1];
      union { uint32_t u[4]; bf16x8 v; } pk;
      pk.u[0] = pack2(a0.x, a0.y); pk.u[1] = pack2(a0.z, a0.w);
      pk.u[2] = pack2(a1.x, a1.y); pk.u[3] = pack2(a1.z, a1.w);
#pragma unroll
      for (int nt = 0; nt < GEMM_NT; ++nt)
        acc[nt] = __builtin_amdgcn_mfma_f32_16x16x32_bf16(pk.v, bfrag[nt][ks], acc[nt], 0, 0, 0);
    }
#pragma unroll
    for (int nt = 0; nt < GEMM_NT; ++nt) {
      const int col = wv * 96 + nt * 16 + l15;
#pragma unroll
      for (int i = 0; i < 4; ++i) {
        const int row = lk * 4 + i;
        *(uint16_t*)(lds_raw + row * LDSROW + col * 2) = f2bf(acc[nt][i] + bias[nt]);
      }
    }
    __syncthreads();
    {
      const int row = tid >> 5, c = tid & 31;
      const uint4* src = (const uint4*)(lds_raw + row * LDSROW + c * 48);
      uint4* dst = (uint4*)((uint8_t*)gi + (size_t)(m0 + row) * G3 * 2 + c * 48);
      dst[0] = src[0]; dst[1] = src[1]; dst[2] = src[2];
    }
    __syncthreads();
  }
}

// ---------------------------------------------------------------------------
// Phase 2: serial scan. 128 WGs x 512 thr. j = tid>>1, q = tid&1.
// hbuf layout: buffer nb occupies uint4 [nb][0..33]; q=0 half at idx 0..15,
// q=1 half at idx 17..32 (skew => disjoint bank groups for the 2-addr read).
// ---------------------------------------------------------------------------
#define DOT4(HV, BASE)                                        \
  do {                                                        \
    _Pragma("unroll")                                         \
    for (int p = 0; p < 4; ++p) {                             \
      const int w0 = (BASE + p) * 4;                          \
      ar = dot2bf(wr[w0 + 0], HV[p].x, ar);                   \
      az = dot2bf(wz[w0 + 0], HV[p].x, az);                   \
      an = dot2bf(wn[w0 + 0], HV[p].x, an);                   \
      ar = dot2bf(wr[w0 + 1], HV[p].y, ar);                   \
      az = dot2bf(wz[w0 + 1], HV[p].y, az);                   \
      an = dot2bf(wn[w0 + 1], HV[p].y, an);                   \
      ar = dot2bf(wr[w0 + 2], HV[p].z, ar);                   \
      az = dot2bf(wz[w0 + 2], HV[p].z, az);                   \
      an = dot2bf(wn[w0 + 2], HV[p].z, an);                   \
      ar = dot2bf(wr[w0 + 3], HV[p].w, ar);                   \
      az = dot2bf(wz[w0 + 3], HV[p].w, az);                   \
      an = dot2bf(wn[w0 + 3], HV[p].w, an);                   \
    }                                                         \
  } while (0)

__global__ __launch_bounds__(512, 1)
void gru_scan(const uint16_t* __restrict__ gi, const float* __restrict__ w_hh,
              const float* __restrict__ b_hh, const float* __restrict__ h0,
              float* __restrict__ hstate, float* __restrict__ out,
              int t0, int cT) {
  __shared__ __align__(16) uint4 hbuf[2][34];
  const int b   = blockIdx.x;
  const int tid = threadIdx.x;
  const int j   = tid >> 1;   // hidden unit 0..255
  const int q   = tid & 1;    // k-half 0..1
  const int hq  = q * 17;     // skewed base for this k-half

  // First-step gi loads (issued early, covered by weight preload)
  const uint16_t* gib = gi + (size_t)b * G3 + j;
  float gr = bf2f(gib[0]), gz = bf2f(gib[256]), gn = bf2f(gib[512]);

  // Weight preload: 3 gates x 64 packed bf16 pairs (k-half q) = 192 VGPRs
  uint32_t wr[64], wz[64], wn[64];
#pragma unroll
  for (int p = 0; p < 64; ++p) {
    float2 a = ((const float2*)(w_hh + (size_t)(0 * 256 + j) * HDIM + q * 128))[p];
    float2 c = ((const float2*)(w_hh + (size_t)(1 * 256 + j) * HDIM + q * 128))[p];
    float2 d = ((const float2*)(w_hh + (size_t)(2 * 256 + j) * HDIM + q * 128))[p];
    wr[p] = pack2(a.x, a.y);
    wz[p] = pack2(c.x, c.y);
    wn[p] = pack2(d.x, d.y);
  }
  const float bhr = b_hh[j], bhz = b_hh[256 + j], bhn = b_hh[512 + j];

  float h = (t0 == 0) ? h0[b * HDIM + j] : hstate[b * HDIM + j];
  // element j -> uint16 idx j + 8*(j>=128) within a buffer (272 uint16 each)
  const int hwidx = j + ((j >> 7) << 3);
  if (q == 0) ((uint16_t*)hbuf)[hwidx] = f2bf(h);
  __syncthreads();

  float* outp = out + (size_t)t0 * BATCH * HDIM + (size_t)b * HDIM + j;

  for (int tt = 0; tt < cT; ++tt) {
    const int cur = tt & 1;
    // Prefetch next step's gi (latency hidden under the dot chain)
    float grn = 0.f, gzn = 0.f, gnn = 0.f;
    if (tt + 1 < cT) {
      const uint16_t* p2 = gib + (size_t)(tt + 1) * BATCH * G3;
      grn = bf2f(p2[0]); gzn = bf2f(p2[256]); gnn = bf2f(p2[512]);
    }

    float ar = 0.f, az = 0.f, an = 0.f;
    // Software-pipelined h reads: 4 batches of 4 x ds_read_b128 (32 live regs)
    uint4 hva[4], hvb[4];
#pragma unroll
    for (int p = 0; p < 4; ++p) hva[p] = hbuf[cur][hq + p];
#pragma unroll
    for (int p = 0; p < 4; ++p) hvb[p] = hbuf[cur][hq + 4 + p];
    DOT4(hva, 0);
#pragma unroll
    for (int p = 0; p < 4; ++p) hva[p] = hbuf[cur][hq + 8 + p];
    DOT4(hvb, 4);
#pragma unroll
    for (int p = 0; p < 4; ++p) hvb[p] = hbuf[cur][hq + 12 + p];
    DOT4(hva, 8);
    DOT4(hvb, 12);

    // k-half reduce: adjacent lanes (same j, q=0/1)
    ar += __shfl_xor(ar, 1);
    az += __shfl_xor(az, 1);
    an += __shfl_xor(an, 1);

    // Gates (computed redundantly by both q-lanes; no divergence)
    float sr = gr + ar + bhr;
    float sz = gz + az + bhz;
    float hn = an + bhn;
    float r = 1.f / (1.f + __expf(-sr));
    float z = 1.f / (1.f + __expf(-sz));
    float xn = gn + r * hn;
    float e = __expf(-2.f * xn);
    float n = 1.f - 2.f * e / (1.f + e);    // tanh(xn)
    h = (1.f - z) * n + z * h;

    if (q == 0) {
      outp[(size_t)tt * BATCH * HDIM] = h;
      ((uint16_t*)hbuf)[(cur ^ 1) * 272 + hwidx] = f2bf(h);
    }
    gr = grn; gz = gzn; gn = gnn;
    __syncthreads();
  }

  if (q == 0) {
    hstate[b * HDIM + j] = h;
    if (t0 + cT == T_SEQ)
      out[(size_t)T_SEQ * BATCH * HDIM + (size_t)b * HDIM + j] = h;
  }
}

// ---------------------------------------------------------------------------
extern "C" void kernel_launch(void* const* d_in, const int* in_sizes, int n_in,
                              void* d_out, int out_size, void* d_ws, size_t ws_size,
                              hipStream_t stream) {
  const float* x    = (const float*)d_in[0];
  const float* h0   = (const float*)d_in[1];
  const float* w_ih = (const float*)d_in[2];
  const float* w_hh = (const float*)d_in[3];
  const float* b_ih = (const float*)d_in[4];
  const float* b_hh = (const float*)d_in[5];
  float* out = (float*)d_out;

  const size_t HST = 1 << 17;  // 128 KB reserved for fp32 h carry state
  float* hstate = (float*)d_ws;
  uint16_t* gi = (uint16_t*)((char*)d_ws + HST);

  const size_t per_t = (size_t)BATCH * G3 * 2;  // bytes of gi per timestep
  size_t cap = (ws_size > HST) ? (ws_size - HST) / per_t : 0;
  int chunk = (int)((cap < (size_t)T_SEQ) ? cap : (size_t)T_SEQ);
  if (chunk < 1) chunk = 1;

  for (int t0 = 0; t0 < T_SEQ; t0 += chunk) {
    const int cT = (T_SEQ - t0 < chunk) ? (T_SEQ - t0) : chunk;
    const int tiles = cT * BATCH / 16;
    gi_gemm<<<256, 512, 0, stream>>>(x + (size_t)t0 * BATCH * IDIM, w_ih, b_ih, gi, tiles);
    gru_scan<<<128, 512, 0, stream>>>(gi, w_hh, b_hh, h0, hstate, out, t0, cT);
  }
}